// Round 1
// 380.298 us; speedup vs baseline: 1.0408x; 1.0408x over previous
//
#include <hip/hip_runtime.h>
#include <hip/hip_bf16.h>

typedef unsigned short u16;
typedef unsigned int u32;
typedef unsigned long long u64;
typedef __attribute__((ext_vector_type(8))) short short8;
typedef __attribute__((ext_vector_type(4))) float float4v;

#define B_DIM 64
#define H_DIM 2048
#define K_DIM 256
#define NTHR  256

// workspace layout (bytes)
#define WS_WBF   0ull                         // 2048*2048*2 = 8388608
#define WS_AQ    (8388608ull)                 // 128*2048*2  = 524288
#define WS_Q     (WS_AQ + 524288ull)          // 64*2048*4   = 524288
#define WS_KN2   (WS_Q + 524288ull)           // 16384*4
#define WS_DOTS  (WS_KN2 + 65536ull)          // 16384*4
#define WS_KBF   (WS_DOTS + 65536ull)         // 16384*2048*2 = 67108864

__device__ __forceinline__ u16 f2bf(float f) {
    unsigned int u = __float_as_uint(f);
    unsigned int r = (u + 0x7fffu + ((u >> 16) & 1u)) >> 16;
    return (u16)r;
}

__device__ __forceinline__ u64 pack4(float4v v) {
    u64 a0 = f2bf(v.x), a1 = f2bf(v.y), a2 = f2bf(v.z), a3 = f2bf(v.w);
    return a0 | (a1 << 16) | (a2 << 32) | (a3 << 48);
}

// async global->LDS 16B/lane; lds dest = wave-uniform base + lane*16
__device__ __forceinline__ void llds16(const u16* g, u16* l) {
    __builtin_amdgcn_global_load_lds(
        (__attribute__((address_space(1))) void*)g,
        (__attribute__((address_space(3))) void*)l, 16, 0, 0);
}

// ---- gemm0 (q += in@W^T) tile helper, 128-tile 2-barrier structure (small GEMM,
// unchanged). LDS XOR swizzle proven: SQ_LDS_BANK_CONFLICT=0.
__device__ __forceinline__ void gemm0_tile(const u16* __restrict__ Aq, const u16* __restrict__ Wb,
                                           float* __restrict__ qout, u16* As, u16* Bs,
                                           int nt, int ksplit) {
    const int tid = threadIdx.x;
    const int wave = tid >> 6, lane = tid & 63;
    const int l15 = lane & 15, qd = lane >> 4;
    const int wm = wave >> 1, wn = wave & 1;
    const int n0 = nt * 128;
    const int grow = lane >> 2;
    const int gcol = (((lane & 3) ^ ((lane >> 3) & 3)) * 8);
    const int sw = (l15 >> 1) & 3;
    float4v acc[4][4] = {};
    const int kb0 = ksplit * 512;
    for (int kk = 0; kk < 16; ++kk) {
        const int k0 = kb0 + kk * 32;
        #pragma unroll
        for (int i = 0; i < 2; ++i) {
            const int r = wave * 32 + i * 16;
            llds16(Wb + (size_t)(n0 + r + grow) * H_DIM + k0 + gcol, &Bs[r * 32]);
            llds16(Aq + (size_t)(r + grow) * H_DIM + k0 + gcol, &As[r * 32]);
        }
        __syncthreads();
        short8 af[4], bf_[4];
        #pragma unroll
        for (int mi = 0; mi < 4; ++mi)
            af[mi] = *(const short8*)&As[(wm * 64 + mi * 16 + l15) * 32 + ((qd ^ sw) * 8)];
        #pragma unroll
        for (int ni = 0; ni < 4; ++ni)
            bf_[ni] = *(const short8*)&Bs[(wn * 64 + ni * 16 + l15) * 32 + ((qd ^ sw) * 8)];
        #pragma unroll
        for (int mi = 0; mi < 4; ++mi)
            #pragma unroll
            for (int ni = 0; ni < 4; ++ni)
                acc[mi][ni] = __builtin_amdgcn_mfma_f32_16x16x32_bf16(af[mi], bf_[ni], acc[mi][ni], 0, 0, 0);
        __syncthreads();
    }
    const int n0w = n0 + wn * 64;
    if (wm == 0) {
        #pragma unroll
        for (int mi = 0; mi < 4; ++mi)
            #pragma unroll
            for (int reg = 0; reg < 4; ++reg) {
                const int m = mi * 16 + qd * 4 + reg;   // 0..63 == b
                #pragma unroll
                for (int ni = 0; ni < 4; ++ni)
                    atomicAdd(&qout[m * H_DIM + n0w + ni * 16 + l15], acc[mi][ni][reg]);
            }
    }
}

// ---- k1: W->bf16 + input->Aq + q=bias + zero kn2/dots (grid 4096) ----
__global__ __launch_bounds__(256) void prep_kernel(
        const float* __restrict__ W, const float* __restrict__ input,
        const float* __restrict__ bias, u16* __restrict__ Wb,
        u16* __restrict__ Aq, float* __restrict__ q,
        float* __restrict__ kn2, float* __restrict__ dots) {
    const int gid = blockIdx.x * NTHR + threadIdx.x;   // 0..1048575
    ((u64*)Wb)[gid] = pack4(((const float4v*)W)[gid]);
    if (gid < 65536) {
        u64 v = 0;
        if (gid < 32768) v = pack4(((const float4v*)input)[gid]);
        ((u64*)Aq)[gid] = v;
    }
    if (gid < 32768)
        ((float4v*)q)[gid] = ((const float4v*)bias)[gid & 511];
    if (gid < 4096) ((float4v*)kn2)[gid] = float4v{0.f, 0.f, 0.f, 0.f};
    else if (gid < 8192) ((float4v*)dots)[gid - 4096] = float4v{0.f, 0.f, 0.f, 0.f};
}

// ---- k2: blocks 0-63 gemm0 (q += in@W^T, split-K atomics); blocks 64+ kb->bf16 ----
__global__ __launch_bounds__(256, 4) void mid_kernel(
        const float* __restrict__ kb, const u16* __restrict__ Aq,
        const u16* __restrict__ Wb, float* __restrict__ q, u16* __restrict__ Kbf) {
    __shared__ __align__(16) u16 As[128 * 32];
    __shared__ __align__(16) u16 Bs[128 * 32];
    const int bid = blockIdx.x;
    if (bid < 64) {
        gemm0_tile(Aq, Wb, q, As, Bs, bid & 15, bid >> 4);
    } else {
        const float4v* s4 = (const float4v*)kb;
        u64* d8 = (u64*)Kbf;
        for (int i = (bid - 64) * NTHR + threadIdx.x; i < 8388608; i += 960 * NTHR)
            d8[i] = pack4(s4[i]);
    }
}

// ---- k3: big GEMM, 256x256 tile, BK=32, 8 waves (2M x 4N), 4-deep LDS ring,
// counted-vmcnt pipeline (T3+T4), setprio around MFMA (T5), XCD-aware mapping (T1).
// Ring discipline: while computing tile t, issue stages for tile t+3 into ring
// slot (t+3)&3 == (t-1)&3, whose last reader finished before the end-of-tile-(t-1)
// barrier -> no overwrite race. vmcnt(8) at each tile end leaves tiles t+2,t+3
// (4 loads each) in flight; tail peels 8->4->0.
__global__ __launch_bounds__(512, 2) void gemm_kernel(
        const u16* __restrict__ Kbf, const u16* __restrict__ Wb,
        const float* __restrict__ bias, const float* __restrict__ q,
        float* __restrict__ kn2, float* __restrict__ dots) {
    extern __shared__ __align__(16) u16 lds[];   // 4 slots x (A 8192 + B 8192) u16 = 128 KiB
    const int tid = threadIdx.x;
    const int wave = tid >> 6, lane = tid & 63;
    const int l15 = lane & 15, qd = lane >> 4;
    const int wm = wave >> 2, wn = wave & 3;
    const int nt = blockIdx.x & 7, mt = blockIdx.x >> 3;  // nt==XCD: B-panel (1MB) L2-resident
    const int m0 = mt * 256, n0 = nt * 256;
    const int grow = wave * 16 + (lane >> 2);             // staging row within 128-row round
    const int gcol = (((lane & 3) ^ ((lane >> 3) & 3)) * 8);  // source-side XOR swizzle
    const int sw = (l15 >> 1) & 3;                        // read-side XOR swizzle

    const u16* srcA = Kbf + (size_t)(m0 + grow) * H_DIM + gcol;
    const u16* srcB = Wb + (size_t)(n0 + grow) * H_DIM + gcol;
    u16* dstBase = lds + wave * 512;                      // wave-uniform LDS dest base

    auto stageA = [&](int t) {
        u16* d = dstBase + (t & 3) * 16384;
        const u16* s = srcA + t * 32;
        llds16(s, d);                                     // rows 0..127 of tile
        llds16(s + (size_t)128 * H_DIM, d + 4096);        // rows 128..255
    };
    auto stageB = [&](int t) {
        u16* d = dstBase + (t & 3) * 16384 + 8192;
        const u16* s = srcB + t * 32;
        llds16(s, d);
        llds16(s + (size_t)128 * H_DIM, d + 4096);
    };

    const int aoff = (wm * 128 + l15) * 32 + ((qd ^ sw) * 8);
    const int boff = (wn * 64 + l15) * 32 + ((qd ^ sw) * 8);

    float4v acc[8][4] = {};

    // prologue: stage tiles 0,1,2 (12 loads); wait until tile 0 (oldest 4) landed
    stageA(0); stageB(0); stageA(1); stageB(1); stageA(2); stageB(2);
    asm volatile("s_waitcnt vmcnt(8)" ::: "memory");
    __builtin_amdgcn_sched_barrier(0);
    __builtin_amdgcn_s_barrier();

    for (int t = 0; t < 64; ++t) {
        const u16* As = lds + (t & 3) * 16384;
        const u16* Bs = As + 8192;
        short8 af[4], bf_[4];
        // ---- phase 0: ds_read B[0..3] + A[0..3], stage A-half of t+3, MFMA mh=0 ----
        #pragma unroll
        for (int ni = 0; ni < 4; ++ni)
            bf_[ni] = *(const short8*)&Bs[boff + ni * 512];
        #pragma unroll
        for (int mi = 0; mi < 4; ++mi)
            af[mi] = *(const short8*)&As[aoff + mi * 512];
        if (t + 3 < 64) stageA(t + 3);
        __builtin_amdgcn_s_barrier();
        asm volatile("s_waitcnt lgkmcnt(0)" ::: "memory");
        __builtin_amdgcn_sched_barrier(0);               // rule #18: pin MFMA below lgkmcnt
        __builtin_amdgcn_s_setprio(1);
        #pragma unroll
        for (int mi = 0; mi < 4; ++mi)
            #pragma unroll
            for (int ni = 0; ni < 4; ++ni)
                acc[mi][ni] = __builtin_amdgcn_mfma_f32_16x16x32_bf16(af[mi], bf_[ni], acc[mi][ni], 0, 0, 0);
        __builtin_amdgcn_s_setprio(0);
        __builtin_amdgcn_s_barrier();
        // ---- phase 1: ds_read A[4..7], stage B-half of t+3, MFMA mh=1 ----
        #pragma unroll
        for (int mi = 0; mi < 4; ++mi)
            af[mi] = *(const short8*)&As[aoff + (4 + mi) * 512];
        if (t + 3 < 64) stageB(t + 3);
        __builtin_amdgcn_s_barrier();
        asm volatile("s_waitcnt lgkmcnt(0)" ::: "memory");
        __builtin_amdgcn_sched_barrier(0);
        __builtin_amdgcn_s_setprio(1);
        #pragma unroll
        for (int mi = 0; mi < 4; ++mi)
            #pragma unroll
            for (int ni = 0; ni < 4; ++ni)
                acc[4 + mi][ni] = __builtin_amdgcn_mfma_f32_16x16x32_bf16(af[mi], bf_[ni], acc[4 + mi][ni], 0, 0, 0);
        __builtin_amdgcn_s_setprio(0);
        // tile-end: ensure tile t+1 landed; keep t+2,t+3 in flight (never vmcnt(0) mid-loop)
        if (t <= 60)      { asm volatile("s_waitcnt vmcnt(8)" ::: "memory"); }
        else if (t == 61) { asm volatile("s_waitcnt vmcnt(4)" ::: "memory"); }
        else if (t == 62) { asm volatile("s_waitcnt vmcnt(0)" ::: "memory"); }
        __builtin_amdgcn_sched_barrier(0);
        __builtin_amdgcn_s_barrier();
    }

    // ---- fused epilogue: per-row sum(y^2), sum(y*q) with bias add ----
    const int n0w = n0 + wn * 64;
    float bv[4];
    #pragma unroll
    for (int ni = 0; ni < 4; ++ni) bv[ni] = bias[n0w + ni * 16 + l15];
    #pragma unroll
    for (int mi = 0; mi < 8; ++mi)
        #pragma unroll
        for (int reg = 0; reg < 4; ++reg) {
            const int mloc = mi * 16 + qd * 4 + reg;          // 0..127 within wave tile
            const int mg = m0 + wm * 128 + mloc;              // global row = k*64+b
            const float* qrow = q + (mloc & 63) * H_DIM;      // b = mg & 63 = mloc & 63
            float s2 = 0.f, sd = 0.f;
            #pragma unroll
            for (int ni = 0; ni < 4; ++ni) {
                const float y = acc[mi][ni][reg] + bv[ni];
                const float qv = qrow[n0w + ni * 16 + l15];
                s2 += y * y; sd += y * qv;
            }
            #pragma unroll
            for (int off = 1; off < 16; off <<= 1) {
                s2 += __shfl_xor(s2, off);
                sd += __shfl_xor(sd, off);
            }
            if (l15 == 0) {
                atomicAdd(&kn2[mg], s2);
                atomicAdd(&dots[mg], sd);
            }
        }
}

// ---- k4: per-b softmax (recomputed per slice-block) + out = input + sum_k attn*kb ----
__global__ __launch_bounds__(256) void final_kernel(
        const float* __restrict__ input, const u16* __restrict__ Kbf,
        const float* __restrict__ q, const float* __restrict__ kn2,
        const float* __restrict__ dots, float* __restrict__ out) {
    __shared__ float sm[K_DIM];
    __shared__ float buf[4];
    const int b = blockIdx.x >> 2, hc = blockIdx.x & 3, tid = threadIdx.x;
    // qn
    float s = 0.f;
    #pragma unroll
    for (int i = 0; i < 8; ++i) {
        float v = q[b * H_DIM + i * 256 + tid];
        s += v * v;
    }
    #pragma unroll
    for (int o = 32; o >= 1; o >>= 1) s += __shfl_xor(s, o);
    if ((tid & 63) == 0) buf[tid >> 6] = s;
    __syncthreads();
    const float qn = fmaxf(sqrtf(buf[0] + buf[1] + buf[2] + buf[3]), 1e-8f);
    __syncthreads();
    // score + softmax over k (k == tid)
    const float kn = fmaxf(sqrtf(kn2[tid * B_DIM + b]), 1e-8f);
    const float sc = dots[tid * B_DIM + b] / (qn * kn);
    float mx = sc;
    #pragma unroll
    for (int o = 32; o >= 1; o >>= 1) mx = fmaxf(mx, __shfl_xor(mx, o));
    if ((tid & 63) == 0) buf[tid >> 6] = mx;
    __syncthreads();
    mx = fmaxf(fmaxf(buf[0], buf[1]), fmaxf(buf[2], buf[3]));
    __syncthreads();
    const float e = expf(sc - mx);
    float se = e;
    #pragma unroll
    for (int o = 32; o >= 1; o >>= 1) se += __shfl_xor(se, o);
    if ((tid & 63) == 0) buf[tid >> 6] = se;
    __syncthreads();
    se = buf[0] + buf[1] + buf[2] + buf[3];
    sm[tid] = e / se;
    __syncthreads();
    // weighted sum for this block's 512-float h-slice
    const u32* base = (const u32*)Kbf;
    const int h2 = hc * 256 + tid;             // u32 unit, 0..1023
    float s0 = 0.f, s1 = 0.f;
    #pragma unroll 8
    for (int k = 0; k < K_DIM; ++k) {
        const u32 p = base[(size_t)(k * B_DIM + b) * (H_DIM / 2) + h2];
        const float a = sm[k];
        s0 += a * __uint_as_float(p << 16);
        s1 += a * __uint_as_float(p & 0xffff0000u);
    }
    const int h = h2 * 2;
    float2 iv = *(const float2*)&input[(size_t)b * H_DIM + h];
    float2 r; r.x = iv.x + s0; r.y = iv.y + s1;
    *(float2*)&out[(size_t)b * H_DIM + h] = r;
}

extern "C" void kernel_launch(void* const* d_in, const int* in_sizes, int n_in,
                              void* d_out, int out_size, void* d_ws, size_t ws_size,
                              hipStream_t stream) {
    const float* input = (const float*)d_in[0];
    const float* kb    = (const float*)d_in[1];
    const float* W     = (const float*)d_in[2];
    const float* bias  = (const float*)d_in[3];
    float* out = (float*)d_out;
    char* ws = (char*)d_ws;

    u16*   Wb   = (u16*)(ws + WS_WBF);
    u16*   Aq   = (u16*)(ws + WS_AQ);
    float* q    = (float*)(ws + WS_Q);
    float* kn2  = (float*)(ws + WS_KN2);
    float* dots = (float*)(ws + WS_DOTS);
    u16*   Kbf  = (u16*)(ws + WS_KBF);

    static int lds_set = 0;
    if (!lds_set) {
        hipFuncSetAttribute((const void*)gemm_kernel,
                            hipFuncAttributeMaxDynamicSharedMemorySize, 131072);
        lds_set = 1;
    }

    prep_kernel<<<4096, NTHR, 0, stream>>>(W, input, bias, Wb, Aq, q, kn2, dots);
    mid_kernel<<<1024, NTHR, 0, stream>>>(kb, Aq, Wb, q, Kbf);
    gemm_kernel<<<512, 512, 131072, stream>>>(Kbf, Wb, bias, q, kn2, dots);
    final_kernel<<<256, NTHR, 0, stream>>>(input, Kbf, q, kn2, dots, out);
}